// Round 2
// baseline (249.905 us; speedup 1.0000x reference)
//
#include <hip/hip_runtime.h>
#include <hip/hip_bf16.h>

// ---------------- problem constants ----------------
#define B_    4
#define C_    4
#define Q_    8
#define J_    5
#define T_    15
#define NSIG  65536
#define N2SIG 32768          // after first decimation
#define NOUT  16384          // after second decimation
#define NCH   (B_ * C_)      // 16 depthwise channels

// ---------------- wavelet filters (from reference, fp32) ----------------
__constant__ float cH0O[13] = {
    -0.00455690456024f, -0.00543947593727f,  0.01702522388155f,  0.02382538479492f,
    -0.10671180468666f,  0.01186609203379f,  0.56881042071212f,  0.75614564389252f,
     0.27529538466888f, -0.11720388769911f, -0.03887280126882f,  0.03466034684485f,
    -0.00388321199915f };
// H1O = (-1)^i * H0O[::-1]
__constant__ float cH1O[13] = {
    -0.00388321199915f, -0.03466034684485f, -0.03887280126882f,  0.11720388769911f,
     0.27529538466888f, -0.75614564389252f,  0.56881042071212f, -0.01186609203379f,
    -0.10671180468666f, -0.02382538479492f,  0.01702522388155f,  0.00543947593727f,
    -0.00455690456024f };
__constant__ float cH0A[10] = {
     0.03516384f, 0.0f, -0.08832942f, 0.23389032f, 0.76027237f,
     0.58751830f, 0.0f, -0.11430184f, 0.0f, 0.0f };
__constant__ float cH0B[10] = {   // H0A reversed
     0.0f, 0.0f, -0.11430184f, 0.0f, 0.58751830f,
     0.76027237f, 0.23389032f, -0.08832942f, 0.0f, 0.03516384f };
__constant__ float cH1A[10] = {   // (-1)^i * H0B
     0.0f, 0.0f, -0.11430184f, 0.0f, 0.58751830f,
    -0.76027237f, 0.23389032f, 0.08832942f, 0.0f, -0.03516384f };
__constant__ float cH1B[10] = {   // H1A reversed
    -0.03516384f, 0.0f, 0.08832942f, 0.23389032f, -0.76027237f,
     0.58751830f, 0.0f, -0.11430184f, 0.0f, 0.0f };
__constant__ float cInvScale[5] = { 1.0f, 0.70710678118654752f, 0.5f,
                                    0.35355339059327376f, 0.25f };

// ---------------- fused kernel ----------------
// Per block: (j, channel, tile of 256 final outputs).
// LDS window coords: global n = ofs + p, ofs = 4*m0 - 147.
//   x       loaded  p in [0, 1320)
//   la1     (lv0)   p in [6, 1313)
//   la2/lb2 (lv1)   p in [10, 1308)
//   la3/lb3 (lv2)   p in [19, 1299)
//   la4/lb4 (lv3)   p in [37, 1281)
//   bp_j            p in [73, 73+NB)
#define M2  256                 // final output samples per tile
#define NV  (2 * M2 + 12)       // 524
#define NU  (4 * M2 + 36)       // 1060
#define NB  (NU + 112)          // 1172
#define S_  1320                // x window incl. cumulative halo (73 left, 74 right)

__global__ __launch_bounds__(256) void murenn_all(
        const float* __restrict__ x,
        const float* __restrict__ cw,
        const float* __restrict__ roots,
        const float* __restrict__ beta_p,
        float* __restrict__ out) {
    __shared__ float P0[S_], P1[S_], P2[S_], P3[S_];
    __shared__ float sR[NB], sI[NB], sU[NU], sV[NV];
    const int tid = threadIdx.x;
    const int mt  = blockIdx.x;          // 0..63
    const int ch  = blockIdx.y;          // b*C + c
    const int j   = blockIdx.z;          // 0..4
    const int b   = ch >> 2, c = ch & 3;
    const int d   = (j == 0) ? 1 : (1 << (j - 1));
    const int m0   = mt * M2;
    const int u_lo = 4 * m0 - 18;
    const int v_lo = 2 * m0 - 6;
    const int ofs  = 4 * m0 - 147;       // bp_lo - 73
    const float beta = beta_p[0];
    const float inv_scale = cInvScale[j];
    const float* xc = x + (size_t)ch * NSIG;

    // ---- load x window (zero outside signal) ----
    for (int p = tid; p < S_; p += 256) {
        int g = ofs + p;
        P0[p] = (g >= 0 && g < NSIG) ? xc[g] : 0.f;
    }
    __syncthreads();

    // ---- UDTCWT chain for this j (all branches block-uniform in j) ----
    if (j == 0) {
        // bp0: 13-tap H1O on x; both trees identical
        for (int i = tid; i < NB; i += 256) {
            int p = 73 + i, g = ofs + p;
            float a = 0.f;
            if (g >= 0 && g < NSIG) {
                #pragma unroll
                for (int k = 0; k < 13; k++) a += cH1O[k] * P0[p + k - 6];
            }
            sR[i] = a; sI[i] = a;
        }
    } else {
        // lv0: la1 = conv13(x, H0O) -> P1   (la1 == lb1)
        for (int p = 6 + tid; p < 1313; p += 256) {
            int g = ofs + p;
            float a = 0.f;
            #pragma unroll
            for (int k = 0; k < 13; k++) a += cH0O[k] * P0[p + k - 6];
            P1[p] = (g >= 0 && g < NSIG) ? a : 0.f;
        }
        __syncthreads();
        if (j == 1) {
            for (int i = tid; i < NB; i += 256) {
                int p = 73 + i, g = ofs + p;
                float ra = 0.f, rb = 0.f;
                if (g >= 0 && g < NSIG) {
                    #pragma unroll
                    for (int k = 0; k < 10; k++) {
                        float s = P1[p + k - 4];
                        ra += cH1A[k] * s; rb += cH1B[k] * s;
                    }
                }
                sR[i] = ra; sI[i] = rb;
            }
        } else {
            // lv1 (d=1, pad 4): la2 -> P2, lb2 -> P3
            for (int p = 10 + tid; p < 1308; p += 256) {
                int g = ofs + p;
                float a = 0.f, bb = 0.f;
                #pragma unroll
                for (int k = 0; k < 10; k++) {
                    float s = P1[p + k - 4];
                    a += cH0A[k] * s; bb += cH0B[k] * s;
                }
                bool ok = (g >= 0 && g < NSIG);
                P2[p] = ok ? a : 0.f; P3[p] = ok ? bb : 0.f;
            }
            __syncthreads();
            if (j == 2) {
                for (int i = tid; i < NB; i += 256) {
                    int p = 73 + i, g = ofs + p;
                    float ra = 0.f, rb = 0.f;
                    if (g >= 0 && g < NSIG) {
                        #pragma unroll
                        for (int k = 0; k < 10; k++) {
                            ra += cH1A[k] * P2[p + 2 * k - 9];
                            rb += cH1B[k] * P3[p + 2 * k - 9];
                        }
                    }
                    sR[i] = ra; sI[i] = rb;
                }
            } else {
                // lv2 (d=2, pad 9): la3 -> P0 (x dead), lb3 -> P1 (la1 dead)
                for (int p = 19 + tid; p < 1299; p += 256) {
                    int g = ofs + p;
                    float a = 0.f, bb = 0.f;
                    #pragma unroll
                    for (int k = 0; k < 10; k++) {
                        a  += cH0A[k] * P2[p + 2 * k - 9];
                        bb += cH0B[k] * P3[p + 2 * k - 9];
                    }
                    bool ok = (g >= 0 && g < NSIG);
                    P0[p] = ok ? a : 0.f; P1[p] = ok ? bb : 0.f;
                }
                __syncthreads();
                if (j == 3) {
                    for (int i = tid; i < NB; i += 256) {
                        int p = 73 + i, g = ofs + p;
                        float ra = 0.f, rb = 0.f;
                        if (g >= 0 && g < NSIG) {
                            #pragma unroll
                            for (int k = 0; k < 10; k++) {
                                ra += cH1A[k] * P0[p + 4 * k - 18];
                                rb += cH1B[k] * P1[p + 4 * k - 18];
                            }
                        }
                        sR[i] = ra; sI[i] = rb;
                    }
                } else {
                    // lv3 (d=4, pad 18): la4 -> P2, lb4 -> P3
                    for (int p = 37 + tid; p < 1281; p += 256) {
                        int g = ofs + p;
                        float a = 0.f, bb = 0.f;
                        #pragma unroll
                        for (int k = 0; k < 10; k++) {
                            a  += cH0A[k] * P0[p + 4 * k - 18];
                            bb += cH0B[k] * P1[p + 4 * k - 18];
                        }
                        bool ok = (g >= 0 && g < NSIG);
                        P2[p] = ok ? a : 0.f; P3[p] = ok ? bb : 0.f;
                    }
                    __syncthreads();
                    // j == 4 bandpass (d=8, pad 36)
                    for (int i = tid; i < NB; i += 256) {
                        int p = 73 + i, g = ofs + p;
                        float ra = 0.f, rb = 0.f;
                        if (g >= 0 && g < NSIG) {
                            #pragma unroll
                            for (int k = 0; k < 10; k++) {
                                ra += cH1A[k] * P2[p + 8 * k - 36];
                                rb += cH1B[k] * P3[p + 8 * k - 36];
                            }
                        }
                        sR[i] = ra; sI[i] = rb;
                    }
                }
            }
        }
    }
    __syncthreads();

    // ---- Q learnable convs + modulus + power + 2x (lowpass + ::2) ----
    for (int q = 0; q < Q_; q++) {
        const int o = c * Q_ + q;                      // channel within this j
        float w[T_];
        #pragma unroll
        for (int t = 0; t < T_; t++) w[t] = cw[(size_t)(j * 32 + o) * T_ + t];
        const float root  = roots[j * 32 + o];
        const float alpha = 1.f / (1.f + __expf(-root));

        for (int i = tid; i < NU; i += 256) {
            int n = u_lo + i;
            float uval = 0.f;
            if (n >= 0 && n < NSIG) {
                float r = 0.f, im = 0.f;
                int idx0 = i + 56 - 7 * d;
                #pragma unroll
                for (int t = 0; t < T_; t++) {
                    r  += w[t] * sR[idx0 + t * d];
                    im += w[t] * sI[idx0 + t * d];
                }
                r *= inv_scale; im *= inv_scale;
                float us   = sqrtf(r * r + im * im);
                float base = fmaxf(us, -beta) + beta;
                uval = __expf(alpha * __logf(base));
            }
            sU[i] = uval;
        }
        __syncthreads();

        // first lowpass + ::2
        for (int i = tid; i < NV; i += 256) {
            int p = v_lo + i;
            float v = 0.f;
            if (p >= 0 && p < N2SIG) {
                #pragma unroll
                for (int k = 0; k < 13; k++) v += cH0O[k] * sU[2 * i + k];
            }
            sV[i] = v;
        }
        __syncthreads();

        // second lowpass + ::2 -> final output
        if (tid < M2) {
            float oacc = 0.f;
            #pragma unroll
            for (int k = 0; k < 13; k++) oacc += cH0O[k] * sV[2 * tid + k];
            out[(size_t)(b * (J_ * 32) + j * 32 + o) * NOUT + (m0 + tid)] = oacc;
        }
        __syncthreads();   // before next q overwrites sU/sV
    }
}

// ---------------- launch ----------------
extern "C" void kernel_launch(void* const* d_in, const int* in_sizes, int n_in,
                              void* d_out, int out_size, void* d_ws, size_t ws_size,
                              hipStream_t stream) {
    (void)in_sizes; (void)n_in; (void)out_size; (void)d_ws; (void)ws_size;
    const float* x     = (const float*)d_in[0];
    const float* cw    = (const float*)d_in[1];
    const float* roots = (const float*)d_in[2];
    const float* beta  = (const float*)d_in[3];
    float* out = (float*)d_out;

    dim3 grid(NOUT / M2, NCH, J_);       // (64, 16, 5)
    murenn_all<<<grid, 256, 0, stream>>>(x, cw, roots, beta, out);
}

// Round 3
// 219.445 us; speedup vs baseline: 1.1388x; 1.1388x over previous
//
#include <hip/hip_runtime.h>
#include <hip/hip_bf16.h>

// ---------------- problem constants ----------------
#define B_    4
#define C_    4
#define Q_    8
#define J_    5
#define T_    15
#define NSIG  65536
#define N2SIG 32768          // after first decimation
#define NOUT  16384          // after second decimation
#define NCH   (B_ * C_)      // 16 depthwise channels

// ---------------- wavelet filters (from reference, fp32) ----------------
__constant__ float cH0O[13] = {
    -0.00455690456024f, -0.00543947593727f,  0.01702522388155f,  0.02382538479492f,
    -0.10671180468666f,  0.01186609203379f,  0.56881042071212f,  0.75614564389252f,
     0.27529538466888f, -0.11720388769911f, -0.03887280126882f,  0.03466034684485f,
    -0.00388321199915f };
__constant__ float cH1O[13] = {
    -0.00388321199915f, -0.03466034684485f, -0.03887280126882f,  0.11720388769911f,
     0.27529538466888f, -0.75614564389252f,  0.56881042071212f, -0.01186609203379f,
    -0.10671180468666f, -0.02382538479492f,  0.01702522388155f,  0.00543947593727f,
    -0.00455690456024f };
__constant__ float cH0A[10] = {
     0.03516384f, 0.0f, -0.08832942f, 0.23389032f, 0.76027237f,
     0.58751830f, 0.0f, -0.11430184f, 0.0f, 0.0f };
__constant__ float cH0B[10] = {
     0.0f, 0.0f, -0.11430184f, 0.0f, 0.58751830f,
     0.76027237f, 0.23389032f, -0.08832942f, 0.0f, 0.03516384f };
__constant__ float cH1A[10] = {
     0.0f, 0.0f, -0.11430184f, 0.0f, 0.58751830f,
    -0.76027237f, 0.23389032f, 0.08832942f, 0.0f, -0.03516384f };
__constant__ float cH1B[10] = {
    -0.03516384f, 0.0f, 0.08832942f, 0.23389032f, -0.76027237f,
     0.58751830f, 0.0f, -0.11430184f, 0.0f, 0.0f };
__constant__ float cInvScale[5] = { 1.0f, 0.70710678118654752f, 0.5f,
                                    0.35355339059327376f, 0.25f };

// ---------------- tiling ----------------
#define M2  256                 // final output samples per tile
#define NV  (2 * M2 + 12)       // 524
#define NU  (4 * M2 + 36)       // 1060
#define NB  (NU + 112)          // 1172 (bp window)
#define NBP 1176                // padded
#define S_  1320                // x window incl. cumulative halo (73 left, 74 right)
#define NUP 1064                // padded U plane stride (16B multiple)
#define NVP 528                 // padded V plane stride (16B multiple)

struct UV { float U[4][NUP]; float V[4][NVP]; };
union ShMem { float P[4][S_]; UV uv; };

// ---------------- post-UDTCWT stage, templated on dilation ----------------
template<int D>
__device__ __forceinline__ void post_stage(
        const float* __restrict__ sR, const float* __restrict__ sI,
        UV& uv,
        const float* __restrict__ cw, const float* __restrict__ roots,
        float beta, float inv_scale,
        int j, int b, int c, int m0, int u_lo, int v_lo, int tid,
        float* __restrict__ out) {
    for (int g2 = 0; g2 < 2; g2++) {
        // block-uniform weights and alphas for this group of 4 q's
        float wA[4][T_];
        float al[4];
        #pragma unroll
        for (int qq = 0; qq < 4; qq++) {
            const int o = c * Q_ + g2 * 4 + qq;
            #pragma unroll
            for (int t = 0; t < T_; t++)
                wA[qq][t] = cw[(size_t)(j * 32 + o) * T_ + t];
            al[qq] = 1.f / (1.f + __expf(-roots[j * 32 + o]));
        }

        // ---- u stage: taps in registers, reused across 4 q's ----
        for (int i = tid; i < NU; i += 256) {
            const int n = u_lo + i;
            const bool ok = (n >= 0) && (n < NSIG);
            const int a0 = i + 56 - 7 * D;
            float tR[T_], tI[T_];
            #pragma unroll
            for (int t = 0; t < T_; t++) {
                tR[t] = sR[a0 + t * D];
                tI[t] = sI[a0 + t * D];
            }
            #pragma unroll
            for (int qq = 0; qq < 4; qq++) {
                float r = 0.f, im = 0.f;
                #pragma unroll
                for (int t = 0; t < T_; t++) {
                    r  = fmaf(wA[qq][t], tR[t], r);
                    im = fmaf(wA[qq][t], tI[t], im);
                }
                r *= inv_scale; im *= inv_scale;
                float us   = sqrtf(fmaf(r, r, im * im));
                float base = fmaxf(us, -beta) + beta;
                uv.U[qq][i] = ok ? __expf(al[qq] * __logf(base)) : 0.f;
            }
        }
        __syncthreads();

        // ---- lowpass1 + ::2, float4 reads, 2 v-samples/thread ----
        for (int ii = tid; ii < NV / 2; ii += 256) {
            const int p0 = v_lo + 2 * ii;
            const bool ok0 = (p0 >= 0) && (p0 < N2SIG);
            const bool ok1 = (p0 + 1 >= 0) && (p0 + 1 < N2SIG);
            #pragma unroll
            for (int qq = 0; qq < 4; qq++) {
                const float4* u4 = (const float4*)&uv.U[qq][0];
                float uu[16];
                float4* uup = (float4*)uu;
                uup[0] = u4[ii];     uup[1] = u4[ii + 1];
                uup[2] = u4[ii + 2]; uup[3] = u4[ii + 3];
                float v0 = 0.f, v1 = 0.f;
                #pragma unroll
                for (int k = 0; k < 13; k++) {
                    v0 = fmaf(cH0O[k], uu[k],     v0);
                    v1 = fmaf(cH0O[k], uu[k + 2], v1);
                }
                float2 st;
                st.x = ok0 ? v0 : 0.f;
                st.y = ok1 ? v1 : 0.f;
                ((float2*)&uv.V[qq][0])[ii] = st;
            }
        }
        __syncthreads();

        // ---- lowpass2 + ::2 -> out, float4 reads, 2 outputs/thread ----
        if (tid < M2 / 2) {
            const int ii = tid;
            #pragma unroll
            for (int qq = 0; qq < 4; qq++) {
                const float4* v4 = (const float4*)&uv.V[qq][0];
                float vv[16];
                float4* vvp = (float4*)vv;
                vvp[0] = v4[ii];     vvp[1] = v4[ii + 1];
                vvp[2] = v4[ii + 2]; vvp[3] = v4[ii + 3];
                float o0 = 0.f, o1 = 0.f;
                #pragma unroll
                for (int k = 0; k < 13; k++) {
                    o0 = fmaf(cH0O[k], vv[k],     o0);
                    o1 = fmaf(cH0O[k], vv[k + 2], o1);
                }
                const int o = c * Q_ + g2 * 4 + qq;
                float2 st; st.x = o0; st.y = o1;
                *(float2*)&out[(size_t)(b * (J_ * 32) + j * 32 + o) * NOUT + m0 + 2 * ii] = st;
            }
        }
        // no barrier needed here: next u-stage writes U (not read by lp2),
        // and the u-stage's own __syncthreads orders lp1(g2+1) after lp2(g2).
    }
}

// ---------------- fused kernel ----------------
__global__ __launch_bounds__(256) void murenn_all(
        const float* __restrict__ x,
        const float* __restrict__ cw,
        const float* __restrict__ roots,
        const float* __restrict__ beta_p,
        float* __restrict__ out) {
    __shared__ __align__(16) ShMem S;
    __shared__ __align__(16) float sR[NBP], sI[NBP];
    const int tid = threadIdx.x;
    const int mt  = blockIdx.x;          // 0..63
    const int ch  = blockIdx.y;          // b*C + c
    const int j   = blockIdx.z;          // 0..4
    const int b   = ch >> 2, c = ch & 3;
    const int m0   = mt * M2;
    const int u_lo = 4 * m0 - 18;
    const int v_lo = 2 * m0 - 6;
    const int ofs  = 4 * m0 - 147;       // bp window start - 73
    const float beta = beta_p[0];
    const float inv_scale = cInvScale[j];
    const float* xc = x + (size_t)ch * NSIG;

    // ---- load x window (zero outside signal) ----
    for (int p = tid; p < S_; p += 256) {
        int g = ofs + p;
        S.P[0][p] = (g >= 0 && g < NSIG) ? xc[g] : 0.f;
    }
    __syncthreads();

    // ---- UDTCWT chain for this j (branches block-uniform in j) ----
    if (j == 0) {
        for (int i = tid; i < NB; i += 256) {
            int p = 73 + i, g = ofs + p;
            float a = 0.f;
            if (g >= 0 && g < NSIG) {
                #pragma unroll
                for (int k = 0; k < 13; k++) a += cH1O[k] * S.P[0][p + k - 6];
            }
            sR[i] = a; sI[i] = a;
        }
    } else {
        // lv0: la1 = conv13(x, H0O) -> P[1]
        for (int p = 6 + tid; p < 1313; p += 256) {
            int g = ofs + p;
            float a = 0.f;
            #pragma unroll
            for (int k = 0; k < 13; k++) a += cH0O[k] * S.P[0][p + k - 6];
            S.P[1][p] = (g >= 0 && g < NSIG) ? a : 0.f;
        }
        __syncthreads();
        if (j == 1) {
            for (int i = tid; i < NB; i += 256) {
                int p = 73 + i, g = ofs + p;
                float ra = 0.f, rb = 0.f;
                if (g >= 0 && g < NSIG) {
                    #pragma unroll
                    for (int k = 0; k < 10; k++) {
                        float s = S.P[1][p + k - 4];
                        ra += cH1A[k] * s; rb += cH1B[k] * s;
                    }
                }
                sR[i] = ra; sI[i] = rb;
            }
        } else {
            // lv1 (d=1, pad 4): la2 -> P[2], lb2 -> P[3]
            for (int p = 10 + tid; p < 1308; p += 256) {
                int g = ofs + p;
                float a = 0.f, bb = 0.f;
                #pragma unroll
                for (int k = 0; k < 10; k++) {
                    float s = S.P[1][p + k - 4];
                    a += cH0A[k] * s; bb += cH0B[k] * s;
                }
                bool ok = (g >= 0 && g < NSIG);
                S.P[2][p] = ok ? a : 0.f; S.P[3][p] = ok ? bb : 0.f;
            }
            __syncthreads();
            if (j == 2) {
                for (int i = tid; i < NB; i += 256) {
                    int p = 73 + i, g = ofs + p;
                    float ra = 0.f, rb = 0.f;
                    if (g >= 0 && g < NSIG) {
                        #pragma unroll
                        for (int k = 0; k < 10; k++) {
                            ra += cH1A[k] * S.P[2][p + 2 * k - 9];
                            rb += cH1B[k] * S.P[3][p + 2 * k - 9];
                        }
                    }
                    sR[i] = ra; sI[i] = rb;
                }
            } else {
                // lv2 (d=2, pad 9): la3 -> P[0], lb3 -> P[1]
                for (int p = 19 + tid; p < 1299; p += 256) {
                    int g = ofs + p;
                    float a = 0.f, bb = 0.f;
                    #pragma unroll
                    for (int k = 0; k < 10; k++) {
                        a  += cH0A[k] * S.P[2][p + 2 * k - 9];
                        bb += cH0B[k] * S.P[3][p + 2 * k - 9];
                    }
                    bool ok = (g >= 0 && g < NSIG);
                    S.P[0][p] = ok ? a : 0.f; S.P[1][p] = ok ? bb : 0.f;
                }
                __syncthreads();
                if (j == 3) {
                    for (int i = tid; i < NB; i += 256) {
                        int p = 73 + i, g = ofs + p;
                        float ra = 0.f, rb = 0.f;
                        if (g >= 0 && g < NSIG) {
                            #pragma unroll
                            for (int k = 0; k < 10; k++) {
                                ra += cH1A[k] * S.P[0][p + 4 * k - 18];
                                rb += cH1B[k] * S.P[1][p + 4 * k - 18];
                            }
                        }
                        sR[i] = ra; sI[i] = rb;
                    }
                } else {
                    // lv3 (d=4, pad 18): la4 -> P[2], lb4 -> P[3]
                    for (int p = 37 + tid; p < 1281; p += 256) {
                        int g = ofs + p;
                        float a = 0.f, bb = 0.f;
                        #pragma unroll
                        for (int k = 0; k < 10; k++) {
                            a  += cH0A[k] * S.P[0][p + 4 * k - 18];
                            bb += cH0B[k] * S.P[1][p + 4 * k - 18];
                        }
                        bool ok = (g >= 0 && g < NSIG);
                        S.P[2][p] = ok ? a : 0.f; S.P[3][p] = ok ? bb : 0.f;
                    }
                    __syncthreads();
                    // j == 4 bandpass (d=8, pad 36)
                    for (int i = tid; i < NB; i += 256) {
                        int p = 73 + i, g = ofs + p;
                        float ra = 0.f, rb = 0.f;
                        if (g >= 0 && g < NSIG) {
                            #pragma unroll
                            for (int k = 0; k < 10; k++) {
                                ra += cH1A[k] * S.P[2][p + 8 * k - 36];
                                rb += cH1B[k] * S.P[3][p + 8 * k - 36];
                            }
                        }
                        sR[i] = ra; sI[i] = rb;
                    }
                }
            }
        }
    }
    __syncthreads();
    // P buffers dead from here: union region becomes U/V planes.

    if (j == 0)      post_stage<1>(sR, sI, S.uv, cw, roots, beta, inv_scale, j, b, c, m0, u_lo, v_lo, tid, out);
    else if (j == 1) post_stage<1>(sR, sI, S.uv, cw, roots, beta, inv_scale, j, b, c, m0, u_lo, v_lo, tid, out);
    else if (j == 2) post_stage<2>(sR, sI, S.uv, cw, roots, beta, inv_scale, j, b, c, m0, u_lo, v_lo, tid, out);
    else if (j == 3) post_stage<4>(sR, sI, S.uv, cw, roots, beta, inv_scale, j, b, c, m0, u_lo, v_lo, tid, out);
    else             post_stage<8>(sR, sI, S.uv, cw, roots, beta, inv_scale, j, b, c, m0, u_lo, v_lo, tid, out);
}

// ---------------- launch ----------------
extern "C" void kernel_launch(void* const* d_in, const int* in_sizes, int n_in,
                              void* d_out, int out_size, void* d_ws, size_t ws_size,
                              hipStream_t stream) {
    (void)in_sizes; (void)n_in; (void)out_size; (void)d_ws; (void)ws_size;
    const float* x     = (const float*)d_in[0];
    const float* cw    = (const float*)d_in[1];
    const float* roots = (const float*)d_in[2];
    const float* beta  = (const float*)d_in[3];
    float* out = (float*)d_out;

    dim3 grid(NOUT / M2, NCH, J_);       // (64, 16, 5)
    murenn_all<<<grid, 256, 0, stream>>>(x, cw, roots, beta, out);
}

// Round 5
// 184.695 us; speedup vs baseline: 1.3531x; 1.1882x over previous
//
#include <hip/hip_runtime.h>
#include <hip/hip_bf16.h>

typedef float v2f __attribute__((ext_vector_type(2)));

// ---------------- problem constants ----------------
#define B_    4
#define C_    4
#define Q_    8
#define J_    5
#define T_    15
#define NSIG  65536
#define N2SIG 32768
#define NOUT  16384
#define NCH   (B_ * C_)

// ---------------- wavelet filters (constexpr -> inline literals) ----------
constexpr float H0Oc[13] = {
    -0.00455690456024f, -0.00543947593727f,  0.01702522388155f,  0.02382538479492f,
    -0.10671180468666f,  0.01186609203379f,  0.56881042071212f,  0.75614564389252f,
     0.27529538466888f, -0.11720388769911f, -0.03887280126882f,  0.03466034684485f,
    -0.00388321199915f };
constexpr float H1Oc[13] = {
    -0.00388321199915f, -0.03466034684485f, -0.03887280126882f,  0.11720388769911f,
     0.27529538466888f, -0.75614564389252f,  0.56881042071212f, -0.01186609203379f,
    -0.10671180468666f, -0.02382538479492f,  0.01702522388155f,  0.00543947593727f,
    -0.00455690456024f };
constexpr float H0Ac[10] = {
     0.03516384f, 0.0f, -0.08832942f, 0.23389032f, 0.76027237f,
     0.58751830f, 0.0f, -0.11430184f, 0.0f, 0.0f };
constexpr float H0Bc[10] = {
     0.0f, 0.0f, -0.11430184f, 0.0f, 0.58751830f,
     0.76027237f, 0.23389032f, -0.08832942f, 0.0f, 0.03516384f };
constexpr float H1Ac[10] = {
     0.0f, 0.0f, -0.11430184f, 0.0f, 0.58751830f,
    -0.76027237f, 0.23389032f, 0.08832942f, 0.0f, -0.03516384f };
constexpr float H1Bc[10] = {
    -0.03516384f, 0.0f, 0.08832942f, 0.23389032f, -0.76027237f,
     0.58751830f, 0.0f, -0.11430184f, 0.0f, 0.0f };

// fused two-stage lowpass+decimate: out[m] = sum_n g[n] * u[4m + n - 18]
// g[n] = sum_k h[k] * h[n-2k], support 37 taps
struct Gtab { float v[37]; };
constexpr Gtab make_g() {
    Gtab g{};
    for (int n = 0; n < 37; ++n) {
        float s = 0.f;
        for (int k = 0; k < 13; ++k) {
            int l = n - 2 * k;
            if (l >= 0 && l < 13) s += H0Oc[k] * H0Oc[l];
        }
        g.v[n] = s;
    }
    return g;
}
constexpr Gtab cG = make_g();

// ---------------- tiling ----------------
#define M2    256                // final outputs per tile
#define NUcnt 1057               // 4*(M2-1) + 37
#define NUP   1064               // padded U plane stride (v2f elems)
#define NBcnt 1169               // bp pairs needed
#define NBP   1176
#define S_    1320               // x window (halo 73 left / 74 right)

// LDS carve (floats): [0,1320) X | [1320,2640) L1 | PP0=v2f@0 (1320) |
// PP1=v2f@2640 (1320) | U0=v2f@0 (1064) | U1=v2f@2128 (1064) | sRI=v2f@5280 (1176)
#define SMEM_FLOATS (5280 + 2 * NBP)

__device__ __forceinline__ v2f zmask(v2f a, bool ok) {
    if (!ok) { a.x = 0.f; a.y = 0.f; }
    return a;
}

// ---------------- post stage (u + fused downsample), templated on D ------
template<int D>
__device__ __forceinline__ void post_stage(
        const v2f* __restrict__ sRI, v2f* __restrict__ U0, v2f* __restrict__ U1,
        const float* __restrict__ cw, const float* __restrict__ roots,
        float beta, int j, int b, int c, int m0, int mt, int tid,
        float* __restrict__ out) {
    const float lg_is = -0.5f * (float)j;                // log2(inv_scale)
    const float beta2 = beta * exp2f(0.5f * (float)j);   // beta * scale
    const int   u_lo  = 4 * m0 - 18;

    for (int g2 = 0; g2 < 2; ++g2) {
        // uniform weights / alphas for this group of 4 q's
        float w[4][T_], al[4], cq[4];
        #pragma unroll
        for (int qq = 0; qq < 4; ++qq) {
            const int o = c * Q_ + g2 * 4 + qq;
            #pragma unroll
            for (int t = 0; t < T_; t++) w[qq][t] = cw[(size_t)(j * 32 + o) * T_ + t];
            al[qq] = 1.f / (1.f + __expf(-roots[j * 32 + o]));
            cq[qq] = al[qq] * lg_is;
        }

        // ---- u stage: pk-fma on (R,I) pairs ----
        for (int i = tid; i < NUcnt; i += 256) {
            const int n = u_lo + i;
            const bool ok = ((unsigned)n < (unsigned)NSIG);
            const v2f* tp = sRI + (i + 56 - 7 * D);
            v2f taps[T_];
            #pragma unroll
            for (int t = 0; t < T_; t++) taps[t] = tp[t * D];
            float uq[4];
            #pragma unroll
            for (int qq = 0; qq < 4; ++qq) {
                v2f ri; ri.x = 0.f; ri.y = 0.f;
                #pragma unroll
                for (int t = 0; t < T_; t++) ri += w[qq][t] * taps[t];
                float z2 = fmaf(ri.x, ri.x, ri.y * ri.y);
                float us = sqrtf(z2);
                float lg = __log2f(us + beta2);
                float u  = exp2f(fmaf(al[qq], lg, cq[qq]));
                uq[qq] = ok ? u : 0.f;
            }
            v2f p0; p0.x = uq[0]; p0.y = uq[1];
            v2f p1; p1.x = uq[2]; p1.y = uq[3];
            U0[i] = p0; U1[i] = p1;
        }
        __syncthreads();

        // ---- fused 37-tap stride-4 downsample, q-pair packed ----
        {
            const int m = m0 + tid;                 // tid < 256 always
            const bool edge = (mt == 0 && tid < 3) || (mt == 63 && tid >= 253);
            #pragma unroll
            for (int qp = 0; qp < 2; ++qp) {
                const v2f* up = qp ? U1 : U0;
                v2f acc; acc.x = 0.f; acc.y = 0.f;
                #pragma unroll
                for (int n = 0; n < 37; ++n) acc += cG.v[n] * up[4 * tid + n];
                if (edge) {
                    // exact two-stage computation honoring v-plane masking
                    v2f a2; a2.x = 0.f; a2.y = 0.f;
                    for (int k = 0; k < 13; ++k) {
                        int p = 2 * m + k - 6;
                        if (p < 0 || p >= N2SIG) continue;
                        v2f v; v.x = 0.f; v.y = 0.f;
                        for (int l = 0; l < 13; ++l)
                            v += H0Oc[l] * up[4 * tid + 2 * k + l];
                        a2 += H0Oc[k] * v;
                    }
                    acc = a2;
                }
                const int o = c * Q_ + g2 * 4 + 2 * qp;
                out[((size_t)b * 160 + j * 32 + o)     * NOUT + m] = acc.x;
                out[((size_t)b * 160 + j * 32 + o + 1) * NOUT + m] = acc.y;
            }
        }
        __syncthreads();   // protect U planes before next group's writes
    }
}

// ---------------- fused kernel ----------------
__global__ __launch_bounds__(256, 4) void murenn_all(
        const float* __restrict__ x,
        const float* __restrict__ cw,
        const float* __restrict__ roots,
        const float* __restrict__ beta_p,
        float* __restrict__ out) {
    __shared__ __align__(16) float smem[SMEM_FLOATS];
    float* X   = smem;                       // [0,1320)
    float* L1  = smem + S_;                  // [1320,2640)
    v2f*   PP0 = (v2f*)smem;                 // aliases X/L1 (used after dead)
    v2f*   PP1 = (v2f*)(smem + 2 * S_);      // floats [2640,5280)
    v2f*   U0  = (v2f*)smem;                 // aliases PP region (dead then)
    v2f*   U1  = (v2f*)(smem + 2 * NUP);
    v2f*   sRI = (v2f*)(smem + 4 * S_);      // floats [5280, 5280+2352)

    const int tid = threadIdx.x;
    const int mt  = blockIdx.x;              // 0..63
    const int ch  = blockIdx.y;              // b*C + c
    const int j   = blockIdx.z;              // 0..4
    const int b   = ch >> 2, c = ch & 3;
    const int m0  = mt * M2;
    const int ofs = 4 * m0 - 147;            // window start (bp index 0 at p=73)
    const float beta = beta_p[0];
    const float* xc = x + (size_t)ch * NSIG;

    // ---- load x window ----
    for (int p = tid; p < S_; p += 256) {
        int g = ofs + p;
        X[p] = ((unsigned)g < (unsigned)NSIG) ? xc[g] : 0.f;
    }
    __syncthreads();

    // ---- UDTCWT chain (branches block-uniform in j) ----
    if (j == 0) {
        for (int i = tid; i < NBcnt; i += 256) {
            int p = 73 + i, g = ofs + p;
            float a = 0.f;
            #pragma unroll
            for (int k = 0; k < 13; k++) a += H1Oc[k] * X[p + k - 6];
            if ((unsigned)g >= (unsigned)NSIG) a = 0.f;
            v2f r; r.x = a; r.y = a;
            sRI[i] = r;
        }
    } else {
        // lv0: la1 = conv13(x, H0O) -> L1
        for (int p = 6 + tid; p < 1313; p += 256) {
            int g = ofs + p;
            float a = 0.f;
            #pragma unroll
            for (int k = 0; k < 13; k++) a += H0Oc[k] * X[p + k - 6];
            L1[p] = ((unsigned)g < (unsigned)NSIG) ? a : 0.f;
        }
        __syncthreads();
        if (j == 1) {
            for (int i = tid; i < NBcnt; i += 256) {
                int p = 73 + i, g = ofs + p;
                v2f r; r.x = 0.f; r.y = 0.f;
                #pragma unroll
                for (int k = 0; k < 10; k++) {
                    v2f hk; hk.x = H1Ac[k]; hk.y = H1Bc[k];
                    r += hk * L1[p + k - 4];
                }
                sRI[i] = zmask(r, (unsigned)g < (unsigned)NSIG);
            }
        } else {
            // lv1 (d=1, pad 4): (la2,lb2) -> PP1
            for (int p = 10 + tid; p < 1308; p += 256) {
                int g = ofs + p;
                v2f a; a.x = 0.f; a.y = 0.f;
                #pragma unroll
                for (int k = 0; k < 10; k++) {
                    v2f hk; hk.x = H0Ac[k]; hk.y = H0Bc[k];
                    a += hk * L1[p + k - 4];
                }
                PP1[p] = zmask(a, (unsigned)g < (unsigned)NSIG);
            }
            __syncthreads();
            if (j == 2) {
                for (int i = tid; i < NBcnt; i += 256) {
                    int p = 73 + i, g = ofs + p;
                    v2f r; r.x = 0.f; r.y = 0.f;
                    #pragma unroll
                    for (int k = 0; k < 10; k++) {
                        v2f hk; hk.x = H1Ac[k]; hk.y = H1Bc[k];
                        r += hk * PP1[p + 2 * k - 9];
                    }
                    sRI[i] = zmask(r, (unsigned)g < (unsigned)NSIG);
                }
            } else {
                // lv2 (d=2, pad 9): (la3,lb3) -> PP0  (X/L1 dead)
                for (int p = 19 + tid; p < 1299; p += 256) {
                    int g = ofs + p;
                    v2f a; a.x = 0.f; a.y = 0.f;
                    #pragma unroll
                    for (int k = 0; k < 10; k++) {
                        v2f hk; hk.x = H0Ac[k]; hk.y = H0Bc[k];
                        a += hk * PP1[p + 2 * k - 9];
                    }
                    PP0[p] = zmask(a, (unsigned)g < (unsigned)NSIG);
                }
                __syncthreads();
                if (j == 3) {
                    for (int i = tid; i < NBcnt; i += 256) {
                        int p = 73 + i, g = ofs + p;
                        v2f r; r.x = 0.f; r.y = 0.f;
                        #pragma unroll
                        for (int k = 0; k < 10; k++) {
                            v2f hk; hk.x = H1Ac[k]; hk.y = H1Bc[k];
                            r += hk * PP0[p + 4 * k - 18];
                        }
                        sRI[i] = zmask(r, (unsigned)g < (unsigned)NSIG);
                    }
                } else {
                    // lv3 (d=4, pad 18): (la4,lb4) -> PP1 (old PP1 dead)
                    for (int p = 37 + tid; p < 1281; p += 256) {
                        int g = ofs + p;
                        v2f a; a.x = 0.f; a.y = 0.f;
                        #pragma unroll
                        for (int k = 0; k < 10; k++) {
                            v2f hk; hk.x = H0Ac[k]; hk.y = H0Bc[k];
                            a += hk * PP0[p + 4 * k - 18];
                        }
                        PP1[p] = zmask(a, (unsigned)g < (unsigned)NSIG);
                    }
                    __syncthreads();
                    // j == 4 bandpass (d=8, pad 36)
                    for (int i = tid; i < NBcnt; i += 256) {
                        int p = 73 + i, g = ofs + p;
                        v2f r; r.x = 0.f; r.y = 0.f;
                        #pragma unroll
                        for (int k = 0; k < 10; k++) {
                            v2f hk; hk.x = H1Ac[k]; hk.y = H1Bc[k];
                            r += hk * PP1[p + 8 * k - 36];
                        }
                        sRI[i] = zmask(r, (unsigned)g < (unsigned)NSIG);
                    }
                }
            }
        }
    }
    __syncthreads();
    // PP/X/L1 dead: region becomes U planes.

    if (j == 0)      post_stage<1>(sRI, U0, U1, cw, roots, beta, 0, b, c, m0, mt, tid, out);
    else if (j == 1) post_stage<1>(sRI, U0, U1, cw, roots, beta, 1, b, c, m0, mt, tid, out);
    else if (j == 2) post_stage<2>(sRI, U0, U1, cw, roots, beta, 2, b, c, m0, mt, tid, out);
    else if (j == 3) post_stage<4>(sRI, U0, U1, cw, roots, beta, 3, b, c, m0, mt, tid, out);
    else             post_stage<8>(sRI, U0, U1, cw, roots, beta, 4, b, c, m0, mt, tid, out);
}

// ---------------- launch ----------------
extern "C" void kernel_launch(void* const* d_in, const int* in_sizes, int n_in,
                              void* d_out, int out_size, void* d_ws, size_t ws_size,
                              hipStream_t stream) {
    (void)in_sizes; (void)n_in; (void)out_size; (void)d_ws; (void)ws_size;
    const float* x     = (const float*)d_in[0];
    const float* cw    = (const float*)d_in[1];
    const float* roots = (const float*)d_in[2];
    const float* beta  = (const float*)d_in[3];
    float* out = (float*)d_out;

    dim3 grid(NOUT / M2, NCH, J_);       // (64, 16, 5)
    murenn_all<<<grid, 256, 0, stream>>>(x, cw, roots, beta, out);
}